// Round 13
// baseline (253.121 us; speedup 1.0000x reference)
//
#include <hip/hip_runtime.h>

typedef unsigned short u16;
typedef short bf16x8 __attribute__((ext_vector_type(8)));
typedef float f32x4 __attribute__((ext_vector_type(4)));
typedef unsigned short u16x8 __attribute__((ext_vector_type(8)));
typedef unsigned short u16x4 __attribute__((ext_vector_type(4)));

union bfr { unsigned int u[4]; bf16x8 v; };

__device__ __forceinline__ u16 f2bf(float f) {
    unsigned int u = __builtin_bit_cast(unsigned int, f);
    u = (u + 0x7fffu + ((u >> 16) & 1u)) >> 16;
    return (u16)u;
}

// v_cvt_pk_bf16_f32: dst = [bf16(hi) : bf16(lo)] (RNE)
__device__ __forceinline__ unsigned int cvtpk(float lo, float hi) {
    unsigned int r;
    asm("v_cvt_pk_bf16_f32 %0, %1, %2" : "=v"(r) : "v"(lo), "v"(hi));
    return r;
}

// async 16B global -> LDS (dest = wave-uniform base + lane*16)
__device__ __forceinline__ void gload16(const u16* src, u16* lds_dst) {
    __builtin_amdgcn_global_load_lds(
        (const __attribute__((address_space(1))) unsigned int*)src,
        (__attribute__((address_space(3))) unsigned int*)lds_dst, 16, 0, 0);
}

// ---------------------------------------------------------------- prep (tiled transpose) + layernorm
__global__ __launch_bounds__(256) void prep_ln_k(
    const float* __restrict__ x, const float* __restrict__ ctx,
    const float* __restrict__ g1, const float* __restrict__ b1,
    const float* __restrict__ g2, const float* __restrict__ b2,
    const float* __restrict__ Wq, const float* __restrict__ Wkv,
    const float* __restrict__ Wp,
    u16* __restrict__ xn, u16* __restrict__ cn,
    u16* __restrict__ WqT, u16* __restrict__ WkvT, u16* __restrict__ WpT)
{
    const int id = blockIdx.x;
    const int t = threadIdx.x;
    if (id >= 16384) {
        __shared__ float T[64][65];
        int t2 = id - 16384;
        const float* src; u16* dst; int lds, k0, n0;
        if (t2 < 288) { src = Wkv; dst = WkvT; lds = 1536; k0 = (t2 / 24) * 64; n0 = (t2 % 24) * 64; }
        else if (t2 < 432) { int u = t2 - 288; src = Wq; dst = WqT; lds = 768; k0 = (u / 12) * 64; n0 = (u % 12) * 64; }
        else { int u = t2 - 432; src = Wp; dst = WpT; lds = 768; k0 = (u / 12) * 64; n0 = (u % 12) * 64; }
        const int rr = t >> 4, c4 = (t & 15) * 4;
        #pragma unroll
        for (int it = 0; it < 4; it++) {
            int r = rr + it * 16;
            f32x4 v = *(const f32x4*)&src[(long)(k0 + r) * lds + n0 + c4];
            #pragma unroll
            for (int j = 0; j < 4; j++) T[c4 + j][r] = v[j];
        }
        __syncthreads();
        #pragma unroll
        for (int it = 0; it < 4; it++) {
            int r = rr + it * 16;
            u16x4 w;
            #pragma unroll
            for (int j = 0; j < 4; j++) w[j] = f2bf(T[r][c4 + j]);
            *(u16x4*)&dst[(long)(n0 + r) * 768 + k0 + c4] = w;
        }
        return;
    }
    const float* src; const float* g; const float* b; u16* dst;
    if (id < 8192) { src = x + (long)id * 768; g = g1; b = b1; dst = xn + (long)id * 768; }
    else { int r = id - 8192; src = ctx + (long)r * 768; g = g2; b = b2; dst = cn + (long)r * 768; }

    int lane = t & 63, wid = t >> 6;
    float v0 = src[t], v1 = src[t + 256], v2 = src[t + 512];
    float s = v0 + v1 + v2;
    for (int o = 32; o; o >>= 1) s += __shfl_xor(s, o);
    __shared__ float r1[4], r2[4];
    if (!lane) r1[wid] = s;
    __syncthreads();
    float mu = (r1[0] + r1[1] + r1[2] + r1[3]) * (1.0f / 768.0f);
    float d0 = v0 - mu, d1 = v1 - mu, d2 = v2 - mu;
    float q = d0 * d0 + d1 * d1 + d2 * d2;
    for (int o = 32; o; o >>= 1) q += __shfl_xor(q, o);
    if (!lane) r2[wid] = q;
    __syncthreads();
    float var = (r2[0] + r2[1] + r2[2] + r2[3]) * (1.0f / 768.0f);
    float rs = rsqrtf(var + 1e-5f);
    dst[t]       = f2bf(d0 * rs * g[t]       + b[t]);
    dst[t + 256] = f2bf(d1 * rs * g[t + 256] + b[t + 256]);
    dst[t + 512] = f2bf(d2 * rs * g[t + 512] + b[t + 512]);
}

// ---------------------------------------------------------------- fused Q + KV projection
// DIRECT-FROM-L2 GEMM: no LDS, no barriers. All operands L2-resident with
// XCD-chunking (weights 1.1-2.3 MB shared; A-rows ~2-5 MB/XCD, 6-12x reuse).
// Per-frag base pointers + compile-time offsets (24 steps x 64B = 1472B < 4KB
// imm) -> zero per-step address VALU; compiler pipelines loads freely.
// Manual 1-step load-ahead bounds live registers (2 frag sets).
__global__ __launch_bounds__(256) void qkv_k(
    const u16* __restrict__ xn, const u16* __restrict__ cn,
    const u16* __restrict__ WqT, const u16* __restrict__ WkvT,
    const float* __restrict__ bq, const float* __restrict__ bkv,
    u16* __restrict__ Qb, u16* __restrict__ Kb, u16* __restrict__ Vt)
{
    const int id = blockIdx.x;
    const int swz = (id & 7) * 144 + (id >> 3);   // XCD-chunked over 1152
    const int tid = threadIdx.x, lane = tid & 63, wid = tid >> 6;
    const int wr = wid >> 1, wc = wid & 1;
    const int g = lane >> 4, i15 = lane & 15;

    const bool isQ = swz < 384;
    int rt, ct;
    const u16* A; const u16* Bt; const float* bias;
    if (isQ) { rt = swz / 6;  ct = swz % 6;  A = xn; Bt = WqT;  bias = bq; }
    else { int s2 = swz - 384; rt = s2 / 12; ct = s2 % 12; A = cn; Bt = WkvT; bias = bkv; }
    const int row0 = rt * 128, col0 = ct * 128;

    // per-fragment global base pointers (lane-resolved)
    const u16* pa[4]; const u16* pb[4];
    #pragma unroll
    for (int m = 0; m < 4; m++)
        pa[m] = A + (long)(row0 + wr * 64 + m * 16 + i15) * 768 + g * 8;
    #pragma unroll
    for (int n = 0; n < 4; n++)
        pb[n] = Bt + (long)(col0 + wc * 64 + n * 16 + i15) * 768 + g * 8;

    f32x4 acc[4][4] = {};
    bf16x8 av[4], bv[4], av2[4], bv2[4];

    #pragma unroll
    for (int m = 0; m < 4; m++) av[m] = *(const bf16x8*)(pa[m]);
    #pragma unroll
    for (int n = 0; n < 4; n++) bv[n] = *(const bf16x8*)(pb[n]);

    #pragma unroll
    for (int t = 0; t < 24; t += 2) {
        if (t + 1 < 24) {
            #pragma unroll
            for (int m = 0; m < 4; m++) av2[m] = *(const bf16x8*)(pa[m] + (t + 1) * 32);
            #pragma unroll
            for (int n = 0; n < 4; n++) bv2[n] = *(const bf16x8*)(pb[n] + (t + 1) * 32);
        }
        #pragma unroll
        for (int m = 0; m < 4; m++)
            #pragma unroll
            for (int n = 0; n < 4; n++)
                acc[m][n] = __builtin_amdgcn_mfma_f32_16x16x32_bf16(av[m], bv[n], acc[m][n], 0, 0, 0);
        if (t + 2 < 24) {
            #pragma unroll
            for (int m = 0; m < 4; m++) av[m] = *(const bf16x8*)(pa[m] + (t + 2) * 32);
            #pragma unroll
            for (int n = 0; n < 4; n++) bv[n] = *(const bf16x8*)(pb[n] + (t + 2) * 32);
        }
        #pragma unroll
        for (int m = 0; m < 4; m++)
            #pragma unroll
            for (int n = 0; n < 4; n++)
                acc[m][n] = __builtin_amdgcn_mfma_f32_16x16x32_bf16(av2[m], bv2[n], acc[m][n], 0, 0, 0);
    }

    float bv4[4];
    #pragma unroll
    for (int n = 0; n < 4; n++) bv4[n] = bias[col0 + wc * 64 + n * 16 + i15];

    #pragma unroll
    for (int m = 0; m < 4; m++) {
        #pragma unroll
        for (int n = 0; n < 4; n++) {
            const int col = col0 + wc * 64 + n * 16 + i15;
            #pragma unroll
            for (int r = 0; r < 4; r++) {
                const int row = row0 + wr * 64 + m * 16 + g * 4 + r;
                float v = acc[m][n][r];
                if (isQ) {
                    v = (v + bv4[n]) * 0.14724444706f;   // 96^-0.5 * log2(e)
                    int b = row >> 10, l = row & 1023;
                    int h = col / 96, d = col % 96;
                    Qb[((long)(b * 8 + h) * 1024 + l) * 96 + d] = f2bf(v);
                } else {
                    v += bv4[n];
                    int b = row >> 10, mt = row & 1023;
                    if (col < 768) {
                        int h = col / 96, d = col % 96;
                        Kb[((long)(b * 8 + h) * 1024 + mt) * 96 + d] = f2bf(v);
                    } else {
                        int cc = col - 768;
                        int h = cc / 96, d = cc % 96;
                        Vt[((long)(b * 8 + h) * 96 + d) * 1024 + mt] = f2bf(v);
                    }
                }
            }
        }
    }
}

// ---------------------------------------------------------------- fused flash attention (r12 form)
__global__ __launch_bounds__(256) void flash_k(
    const u16* __restrict__ Qb, const u16* __restrict__ Kb,
    const u16* __restrict__ Vt, u16* __restrict__ Ob)
{
    const int i = blockIdx.x;
    const int s8 = i >> 3;
    const int bh = (i & 7) * 8 + (s8 >> 4);   // XCD-grouped: 8 bh per XCD
    const int qt = s8 & 15;
    const int tid = threadIdx.x, lane = tid & 63, wid = tid >> 6;
    const int g = lane >> 4, i15 = lane & 15;

    __shared__ u16 Ks[2][6144];   // [kd][row][32] per buffer, twisted slots
    __shared__ u16 Vs[2][6144];   // [96][64] swizzled, 12 KB

    const long baseQK = (long)bh * 98304;
    const u16* Kt  = Kb + baseQK;
    const u16* Vtp = Vt + baseQK;

    bf16x8 qf[3];
    {
        const u16* qrow = Qb + baseQK + (long)(qt * 64 + wid * 16 + i15) * 96 + g * 8;
        qf[0] = *(const bf16x8*)(qrow);
        qf[1] = *(const bf16x8*)(qrow + 32);
        qf[2] = *(const bf16x8*)(qrow + 64);
    }

    int krd[4][3];
    #pragma unroll
    for (int n = 0; n < 4; n++) {
        int q4 = i15 >> 2, rr = i15 & 3, m = n >> 1;
        int R = (n & 1) ? (m * 32 + ((q4 ^ 2) << 3) + 4 + rr)
                        : (m * 32 + (q4 << 3) + rr);
        #pragma unroll
        for (int kd = 0; kd < 3; kd++)
            krd[n][kd] = kd * 2048 + R * 32 + ((g ^ ((R >> 3) & 3) ^ kd) << 3);
    }
    int vrd[6][2];
    #pragma unroll
    for (int n6 = 0; n6 < 6; n6++) {
        int row = n6 * 16 + i15;
        #pragma unroll
        for (int kk = 0; kk < 2; kk++)
            vrd[n6][kk] = row * 64 + ((kk * 32 + g * 8) ^ ((row & 7) << 3));
    }

    int kgo[3], kwr[3], vgo[3], vwr[3];
    #pragma unroll
    for (int it = 0; it < 3; it++) {
        int e = tid + it * 256;
        int r = e / 12, cEl = (e % 12) * 8;
        int kd = cEl >> 5, slot = (cEl >> 3) & 3;
        kgo[it] = r * 96 + cEl;
        kwr[it] = kd * 2048 + r * 32 + ((slot ^ ((r >> 3) & 3) ^ kd) << 3);
        int d = e >> 3, m8 = (e & 7) * 8;
        vgo[it] = d * 1024 + m8;
        vwr[it] = d * 64 + (m8 ^ ((d & 7) << 3));
    }

    u16x8 kreg[3], vreg[3];
    #pragma unroll
    for (int it = 0; it < 3; it++) {
        kreg[it] = *(const u16x8*)&Kt[kgo[it]];
        vreg[it] = *(const u16x8*)&Vtp[vgo[it]];
    }
    #pragma unroll
    for (int it = 0; it < 3; it++) {
        *(u16x8*)&Ks[0][kwr[it]] = kreg[it];
        *(u16x8*)&Vs[0][vwr[it]] = vreg[it];
    }

    f32x4 o[6] = {};
    float lsum = 0.f;
    int cur = 0;

    for (int t = 0; t < 16; t++) {
        __syncthreads();
        if (t < 15) {
            #pragma unroll
            for (int it = 0; it < 3; it++) {
                kreg[it] = *(const u16x8*)&Kt[(t + 1) * 6144 + kgo[it]];
                vreg[it] = *(const u16x8*)&Vtp[(t + 1) * 64 + vgo[it]];
            }
        }

        f32x4 s[4] = {};
        #pragma unroll
        for (int kd = 0; kd < 3; kd++) {
            #pragma unroll
            for (int n = 0; n < 4; n++) {
                bf16x8 kf = *(const bf16x8*)&Ks[cur][krd[n][kd]];
                s[n] = __builtin_amdgcn_mfma_f32_16x16x32_bf16(kf, qf[kd], s[n], 0, 0, 0);
            }
        }

        unsigned int pk[4][2];
        #pragma unroll
        for (int n = 0; n < 4; n++) {
            float p0 = exp2f(s[n][0]), p1 = exp2f(s[n][1]);
            float p2 = exp2f(s[n][2]), p3 = exp2f(s[n][3]);
            lsum += (p0 + p1) + (p2 + p3);
            pk[n][0] = cvtpk(p0, p1);
            pk[n][1] = cvtpk(p2, p3);
        }

        #pragma unroll
        for (int kk = 0; kk < 2; kk++) {
            bfr pa;
            pa.u[0] = pk[kk * 2][0];
            pa.u[1] = pk[kk * 2][1];
            pa.u[2] = __shfl_xor(pk[kk * 2 + 1][0], 32);
            pa.u[3] = __shfl_xor(pk[kk * 2 + 1][1], 32);
            #pragma unroll
            for (int n6 = 0; n6 < 6; n6++) {
                bf16x8 vf = *(const bf16x8*)&Vs[cur][vrd[n6][kk]];
                o[n6] = __builtin_amdgcn_mfma_f32_16x16x32_bf16(pa.v, vf, o[n6], 0, 0, 0);
            }
        }

        if (t < 15) {
            #pragma unroll
            for (int it = 0; it < 3; it++) {
                *(u16x8*)&Ks[cur ^ 1][kwr[it]] = kreg[it];
                *(u16x8*)&Vs[cur ^ 1][vwr[it]] = vreg[it];
            }
        }
        cur ^= 1;
    }

    lsum += __shfl_xor(lsum, 16);
    lsum += __shfl_xor(lsum, 32);
    float linv = 1.0f / lsum;

    const int b = bh >> 3, h = bh & 7;
    #pragma unroll
    for (int r = 0; r < 4; r++) {
        float lr = __shfl(linv, g * 4 + r);
        int row = qt * 64 + wid * 16 + g * 4 + r;
        long base = ((long)(b * 1024 + row)) * 768 + h * 96;
        #pragma unroll
        for (int n6 = 0; n6 < 6; n6++)
            Ob[base + n6 * 16 + i15] = f2bf(o[n6][r] * lr);
    }
}

// ---------------------------------------------------------------- out projection (direct-from-L2) + attn_map
__global__ __launch_bounds__(256) void out_k(
    const u16* __restrict__ Ob, const u16* __restrict__ WpT,
    const float* __restrict__ bp, const float* __restrict__ resid,
    float* __restrict__ out, float* __restrict__ amap)
{
    const int id = blockIdx.x;
    if (id >= 384) {
        amap[(id - 384) * 256 + threadIdx.x] = 1.0f;
        return;
    }
    const int swz = (id & 7) * 48 + (id >> 3);
    const int rt = swz / 6, ct = swz % 6;
    const int row0 = rt * 128, col0 = ct * 128;
    const int tid = threadIdx.x, lane = tid & 63, wid = tid >> 6;
    const int wr = wid >> 1, wc = wid & 1;
    const int g = lane >> 4, i15 = lane & 15;

    const u16* pa[4]; const u16* pb[4];
    #pragma unroll
    for (int m = 0; m < 4; m++)
        pa[m] = Ob + (long)(row0 + wr * 64 + m * 16 + i15) * 768 + g * 8;
    #pragma unroll
    for (int n = 0; n < 4; n++)
        pb[n] = WpT + (long)(col0 + wc * 64 + n * 16 + i15) * 768 + g * 8;

    f32x4 acc[4][4] = {};
    bf16x8 av[4], bv[4], av2[4], bv2[4];

    #pragma unroll
    for (int m = 0; m < 4; m++) av[m] = *(const bf16x8*)(pa[m]);
    #pragma unroll
    for (int n = 0; n < 4; n++) bv[n] = *(const bf16x8*)(pb[n]);

    #pragma unroll
    for (int t = 0; t < 24; t += 2) {
        if (t + 1 < 24) {
            #pragma unroll
            for (int m = 0; m < 4; m++) av2[m] = *(const bf16x8*)(pa[m] + (t + 1) * 32);
            #pragma unroll
            for (int n = 0; n < 4; n++) bv2[n] = *(const bf16x8*)(pb[n] + (t + 1) * 32);
        }
        #pragma unroll
        for (int m = 0; m < 4; m++)
            #pragma unroll
            for (int n = 0; n < 4; n++)
                acc[m][n] = __builtin_amdgcn_mfma_f32_16x16x32_bf16(av[m], bv[n], acc[m][n], 0, 0, 0);
        if (t + 2 < 24) {
            #pragma unroll
            for (int m = 0; m < 4; m++) av[m] = *(const bf16x8*)(pa[m] + (t + 2) * 32);
            #pragma unroll
            for (int n = 0; n < 4; n++) bv[n] = *(const bf16x8*)(pb[n] + (t + 2) * 32);
        }
        #pragma unroll
        for (int m = 0; m < 4; m++)
            #pragma unroll
            for (int n = 0; n < 4; n++)
                acc[m][n] = __builtin_amdgcn_mfma_f32_16x16x32_bf16(av2[m], bv2[n], acc[m][n], 0, 0, 0);
    }

    float bv4[4];
    #pragma unroll
    for (int n = 0; n < 4; n++) bv4[n] = bp[col0 + wc * 64 + n * 16 + i15];

    #pragma unroll
    for (int m = 0; m < 4; m++) {
        #pragma unroll
        for (int n = 0; n < 4; n++) {
            const int col = col0 + wc * 64 + n * 16 + i15;
            #pragma unroll
            for (int r = 0; r < 4; r++) {
                const int row = row0 + wr * 64 + m * 16 + g * 4 + r;
                long idx = (long)row * 768 + col;
                out[idx] = acc[m][n][r] + bv4[n] + resid[idx];
            }
        }
    }
}

extern "C" void kernel_launch(void* const* d_in, const int* in_sizes, int n_in,
                              void* d_out, int out_size, void* d_ws, size_t ws_size,
                              hipStream_t stream)
{
    const float* x   = (const float*)d_in[0];
    const float* ctx = (const float*)d_in[1];
    const float* Wq  = (const float*)d_in[2];
    const float* bq  = (const float*)d_in[3];
    const float* Wkv = (const float*)d_in[4];
    const float* bkv = (const float*)d_in[5];
    const float* Wp  = (const float*)d_in[6];
    const float* bp  = (const float*)d_in[7];
    const float* g1  = (const float*)d_in[8];
    const float* b1  = (const float*)d_in[9];
    const float* g2  = (const float*)d_in[10];
    const float* b2  = (const float*)d_in[11];
    float* out = (float*)d_out;

    char* w = (char*)d_ws;
    const long SZ_ROWS = 8192L * 768 * 2;   // 12,582,912 B
    long off = 0;
    u16* xn   = (u16*)(w + off); off += SZ_ROWS;
    u16* cn   = (u16*)(w + off); off += SZ_ROWS;
    u16* WqT  = (u16*)(w + off); off += 768L * 768 * 2;
    u16* WkvT = (u16*)(w + off); off += 1536L * 768 * 2;
    u16* WpT  = (u16*)(w + off); off += 768L * 768 * 2;
    u16* Qb   = (u16*)(w + off); off += SZ_ROWS;
    u16* Kb   = (u16*)(w + off); off += SZ_ROWS;
    u16* Vt   = (u16*)(w + off); off += SZ_ROWS;
    u16* Ob   = (u16*)(w + off); off += SZ_ROWS;

    prep_ln_k<<<16960, 256, 0, stream>>>(x, ctx, g1, b1, g2, b2, Wq, Wkv, Wp,
                                         xn, cn, WqT, WkvT, WpT);
    qkv_k<<<1152, 256, 0, stream>>>(xn, cn, WqT, WkvT, bq, bkv, Qb, Kb, Vt);
    flash_k<<<1024, 256, 0, stream>>>(Qb, Kb, Vt, Ob);
    out_k<<<416, 256, 0, stream>>>(Ob, WpT, bp, x, out, out + 6291456L);
}

// Round 14
// 163.128 us; speedup vs baseline: 1.5517x; 1.5517x over previous
//
#include <hip/hip_runtime.h>

typedef unsigned short u16;
typedef short bf16x8 __attribute__((ext_vector_type(8)));
typedef float f32x4 __attribute__((ext_vector_type(4)));
typedef unsigned short u16x8 __attribute__((ext_vector_type(8)));
typedef unsigned short u16x4 __attribute__((ext_vector_type(4)));

union bfr { unsigned int u[4]; bf16x8 v; };

__device__ __forceinline__ u16 f2bf(float f) {
    unsigned int u = __builtin_bit_cast(unsigned int, f);
    u = (u + 0x7fffu + ((u >> 16) & 1u)) >> 16;
    return (u16)u;
}

// v_cvt_pk_bf16_f32: dst = [bf16(hi) : bf16(lo)] (RNE)
__device__ __forceinline__ unsigned int cvtpk(float lo, float hi) {
    unsigned int r;
    asm("v_cvt_pk_bf16_f32 %0, %1, %2" : "=v"(r) : "v"(lo), "v"(hi));
    return r;
}

// async 16B global -> LDS (dest = wave-uniform base + lane*16)
__device__ __forceinline__ void gload16(const u16* src, u16* lds_dst) {
    __builtin_amdgcn_global_load_lds(
        (const __attribute__((address_space(1))) unsigned int*)src,
        (__attribute__((address_space(3))) unsigned int*)lds_dst, 16, 0, 0);
}

// ---------------------------------------------------------------- prep (tiled transpose) + layernorm
__global__ __launch_bounds__(256) void prep_ln_k(
    const float* __restrict__ x, const float* __restrict__ ctx,
    const float* __restrict__ g1, const float* __restrict__ b1,
    const float* __restrict__ g2, const float* __restrict__ b2,
    const float* __restrict__ Wq, const float* __restrict__ Wkv,
    const float* __restrict__ Wp,
    u16* __restrict__ xn, u16* __restrict__ cn,
    u16* __restrict__ WqT, u16* __restrict__ WkvT, u16* __restrict__ WpT)
{
    const int id = blockIdx.x;
    const int t = threadIdx.x;
    if (id >= 16384) {
        __shared__ float T[64][65];
        int t2 = id - 16384;
        const float* src; u16* dst; int lds, k0, n0;
        if (t2 < 288) { src = Wkv; dst = WkvT; lds = 1536; k0 = (t2 / 24) * 64; n0 = (t2 % 24) * 64; }
        else if (t2 < 432) { int u = t2 - 288; src = Wq; dst = WqT; lds = 768; k0 = (u / 12) * 64; n0 = (u % 12) * 64; }
        else { int u = t2 - 432; src = Wp; dst = WpT; lds = 768; k0 = (u / 12) * 64; n0 = (u % 12) * 64; }
        const int rr = t >> 4, c4 = (t & 15) * 4;
        #pragma unroll
        for (int it = 0; it < 4; it++) {
            int r = rr + it * 16;
            f32x4 v = *(const f32x4*)&src[(long)(k0 + r) * lds + n0 + c4];
            #pragma unroll
            for (int j = 0; j < 4; j++) T[c4 + j][r] = v[j];
        }
        __syncthreads();
        #pragma unroll
        for (int it = 0; it < 4; it++) {
            int r = rr + it * 16;
            u16x4 w;
            #pragma unroll
            for (int j = 0; j < 4; j++) w[j] = f2bf(T[r][c4 + j]);
            *(u16x4*)&dst[(long)(n0 + r) * 768 + k0 + c4] = w;
        }
        return;
    }
    const float* src; const float* g; const float* b; u16* dst;
    if (id < 8192) { src = x + (long)id * 768; g = g1; b = b1; dst = xn + (long)id * 768; }
    else { int r = id - 8192; src = ctx + (long)r * 768; g = g2; b = b2; dst = cn + (long)r * 768; }

    int lane = t & 63, wid = t >> 6;
    float v0 = src[t], v1 = src[t + 256], v2 = src[t + 512];
    float s = v0 + v1 + v2;
    for (int o = 32; o; o >>= 1) s += __shfl_xor(s, o);
    __shared__ float r1[4], r2[4];
    if (!lane) r1[wid] = s;
    __syncthreads();
    float mu = (r1[0] + r1[1] + r1[2] + r1[3]) * (1.0f / 768.0f);
    float d0 = v0 - mu, d1 = v1 - mu, d2 = v2 - mu;
    float q = d0 * d0 + d1 * d1 + d2 * d2;
    for (int o = 32; o; o >>= 1) q += __shfl_xor(q, o);
    if (!lane) r2[wid] = q;
    __syncthreads();
    float var = (r2[0] + r2[1] + r2[2] + r2[3]) * (1.0f / 768.0f);
    float rs = rsqrtf(var + 1e-5f);
    dst[t]       = f2bf(d0 * rs * g[t]       + b[t]);
    dst[t + 256] = f2bf(d1 * rs * g[t + 256] + b[t + 256]);
    dst[t + 512] = f2bf(d2 * rs * g[t + 512] + b[t + 512]);
}

// ---------------------------------------------------------------- fused Q + KV projection
// r5 2-sync 128x128 structure with BK=64: 12 K-steps (half the barriers/drains),
// 32 MFMA/wave/step. 128B LDS rows -> involution slot' = slot ^ (row&7) applied
// to pre-swizzled global source (linear gload dest) + ds_read twist:
// 16 consecutive rows hit each of 8 slots twice -> 2-way = free.
__global__ __launch_bounds__(256) void qkv_k(
    const u16* __restrict__ xn, const u16* __restrict__ cn,
    const u16* __restrict__ WqT, const u16* __restrict__ WkvT,
    const float* __restrict__ bq, const float* __restrict__ bkv,
    u16* __restrict__ Qb, u16* __restrict__ Kb, u16* __restrict__ Vt)
{
    __shared__ u16 As[128 * 64];   // 16 KB, single buffer (2-sync safe)
    __shared__ u16 Bs[128 * 64];
    const int id = blockIdx.x;
    const int swz = (id & 7) * 144 + (id >> 3);   // XCD-chunked over 1152
    const int tid = threadIdx.x, lane = tid & 63, wid = tid >> 6;
    const int wr = wid >> 1, wc = wid & 1;
    const int g = lane >> 4, i15 = lane & 15;

    const bool isQ = swz < 384;
    int rt, ct;
    const u16* A; const u16* Bt; const float* bias;
    if (isQ) { rt = swz / 6;  ct = swz % 6;  A = xn; Bt = WqT;  bias = bq; }
    else { int s2 = swz - 384; rt = s2 / 12; ct = s2 % 12; A = cn; Bt = WkvT; bias = bkv; }
    const int row0 = rt * 128, col0 = ct * 128;

    // staging: 1024 16B-chunks per matrix, 4/thread; chunk d: r=d>>3, slot=d&7
    const u16* srcA[4]; const u16* srcB[4]; int dstOff[4];
    #pragma unroll
    for (int c = 0; c < 4; c++) {
        int d = tid + c * 256;
        int r = d >> 3, sl = d & 7;
        int colx = ((sl ^ (r & 7)) << 3);        // pre-swizzled source col
        srcA[c] = A  + (long)(row0 + r) * 768 + colx;
        srcB[c] = Bt + (long)(col0 + r) * 768 + colx;
        dstOff[c] = (wid * 64 + c * 256) * 8;    // wave-uniform u16 base
    }

    // twisted fragment read offsets (lane-constant)
    int aoff[4][2], boff[4][2];
    #pragma unroll
    for (int m = 0; m < 4; m++) {
        int R = wr * 64 + m * 16 + i15;
        #pragma unroll
        for (int ks = 0; ks < 2; ks++)
            aoff[m][ks] = R * 64 + (((ks * 4 + g) ^ (R & 7)) << 3);
    }
    #pragma unroll
    for (int n = 0; n < 4; n++) {
        int R = wc * 64 + n * 16 + i15;
        #pragma unroll
        for (int ks = 0; ks < 2; ks++)
            boff[n][ks] = R * 64 + (((ks * 4 + g) ^ (R & 7)) << 3);
    }

    f32x4 acc[4][4] = {};
    for (int t = 0; t < 12; t++) {
        __syncthreads();                          // prev reads done
        #pragma unroll
        for (int c = 0; c < 4; c++) {
            gload16(srcA[c] + t * 64, &As[dstOff[c]]);
            gload16(srcB[c] + t * 64, &Bs[dstOff[c]]);
        }
        __syncthreads();                          // staged (vmcnt drained)
        #pragma unroll
        for (int ks = 0; ks < 2; ks++) {
            bf16x8 av[4], bv[4];
            #pragma unroll
            for (int m = 0; m < 4; m++) av[m] = *(const bf16x8*)&As[aoff[m][ks]];
            #pragma unroll
            for (int n = 0; n < 4; n++) bv[n] = *(const bf16x8*)&Bs[boff[n][ks]];
            #pragma unroll
            for (int m = 0; m < 4; m++)
                #pragma unroll
                for (int n = 0; n < 4; n++)
                    acc[m][n] = __builtin_amdgcn_mfma_f32_16x16x32_bf16(av[m], bv[n], acc[m][n], 0, 0, 0);
        }
    }

    float bv4[4];
    #pragma unroll
    for (int n = 0; n < 4; n++) bv4[n] = bias[col0 + wc * 64 + n * 16 + i15];

    #pragma unroll
    for (int m = 0; m < 4; m++) {
        #pragma unroll
        for (int n = 0; n < 4; n++) {
            const int col = col0 + wc * 64 + n * 16 + i15;
            #pragma unroll
            for (int r = 0; r < 4; r++) {
                const int row = row0 + wr * 64 + m * 16 + g * 4 + r;
                float v = acc[m][n][r];
                if (isQ) {
                    v = (v + bv4[n]) * 0.14724444706f;   // 96^-0.5 * log2(e)
                    int b = row >> 10, l = row & 1023;
                    int h = col / 96, d = col % 96;
                    Qb[((long)(b * 8 + h) * 1024 + l) * 96 + d] = f2bf(v);
                } else {
                    v += bv4[n];
                    int b = row >> 10, mt = row & 1023;
                    if (col < 768) {
                        int h = col / 96, d = col % 96;
                        Kb[((long)(b * 8 + h) * 1024 + mt) * 96 + d] = f2bf(v);
                    } else {
                        int cc = col - 768;
                        int h = cc / 96, d = cc % 96;
                        Vt[((long)(b * 8 + h) * 96 + d) * 1024 + mt] = f2bf(v);
                    }
                }
            }
        }
    }
}

// ---------------------------------------------------------------- fused flash attention (r12 form, unchanged)
__global__ __launch_bounds__(256) void flash_k(
    const u16* __restrict__ Qb, const u16* __restrict__ Kb,
    const u16* __restrict__ Vt, u16* __restrict__ Ob)
{
    const int i = blockIdx.x;
    const int s8 = i >> 3;
    const int bh = (i & 7) * 8 + (s8 >> 4);   // XCD-grouped: 8 bh per XCD
    const int qt = s8 & 15;
    const int tid = threadIdx.x, lane = tid & 63, wid = tid >> 6;
    const int g = lane >> 4, i15 = lane & 15;

    __shared__ u16 Ks[2][6144];   // [kd][row][32] per buffer, twisted slots
    __shared__ u16 Vs[2][6144];   // [96][64] swizzled, 12 KB

    const long baseQK = (long)bh * 98304;
    const u16* Kt  = Kb + baseQK;
    const u16* Vtp = Vt + baseQK;

    bf16x8 qf[3];
    {
        const u16* qrow = Qb + baseQK + (long)(qt * 64 + wid * 16 + i15) * 96 + g * 8;
        qf[0] = *(const bf16x8*)(qrow);
        qf[1] = *(const bf16x8*)(qrow + 32);
        qf[2] = *(const bf16x8*)(qrow + 64);
    }

    int krd[4][3];
    #pragma unroll
    for (int n = 0; n < 4; n++) {
        int q4 = i15 >> 2, rr = i15 & 3, m = n >> 1;
        int R = (n & 1) ? (m * 32 + ((q4 ^ 2) << 3) + 4 + rr)
                        : (m * 32 + (q4 << 3) + rr);
        #pragma unroll
        for (int kd = 0; kd < 3; kd++)
            krd[n][kd] = kd * 2048 + R * 32 + ((g ^ ((R >> 3) & 3) ^ kd) << 3);
    }
    int vrd[6][2];
    #pragma unroll
    for (int n6 = 0; n6 < 6; n6++) {
        int row = n6 * 16 + i15;
        #pragma unroll
        for (int kk = 0; kk < 2; kk++)
            vrd[n6][kk] = row * 64 + ((kk * 32 + g * 8) ^ ((row & 7) << 3));
    }

    int kgo[3], kwr[3], vgo[3], vwr[3];
    #pragma unroll
    for (int it = 0; it < 3; it++) {
        int e = tid + it * 256;
        int r = e / 12, cEl = (e % 12) * 8;
        int kd = cEl >> 5, slot = (cEl >> 3) & 3;
        kgo[it] = r * 96 + cEl;
        kwr[it] = kd * 2048 + r * 32 + ((slot ^ ((r >> 3) & 3) ^ kd) << 3);
        int d = e >> 3, m8 = (e & 7) * 8;
        vgo[it] = d * 1024 + m8;
        vwr[it] = d * 64 + (m8 ^ ((d & 7) << 3));
    }

    u16x8 kreg[3], vreg[3];
    #pragma unroll
    for (int it = 0; it < 3; it++) {
        kreg[it] = *(const u16x8*)&Kt[kgo[it]];
        vreg[it] = *(const u16x8*)&Vtp[vgo[it]];
    }
    #pragma unroll
    for (int it = 0; it < 3; it++) {
        *(u16x8*)&Ks[0][kwr[it]] = kreg[it];
        *(u16x8*)&Vs[0][vwr[it]] = vreg[it];
    }

    f32x4 o[6] = {};
    float lsum = 0.f;
    int cur = 0;

    for (int t = 0; t < 16; t++) {
        __syncthreads();
        if (t < 15) {
            #pragma unroll
            for (int it = 0; it < 3; it++) {
                kreg[it] = *(const u16x8*)&Kt[(t + 1) * 6144 + kgo[it]];
                vreg[it] = *(const u16x8*)&Vtp[(t + 1) * 64 + vgo[it]];
            }
        }

        f32x4 s[4] = {};
        #pragma unroll
        for (int kd = 0; kd < 3; kd++) {
            #pragma unroll
            for (int n = 0; n < 4; n++) {
                bf16x8 kf = *(const bf16x8*)&Ks[cur][krd[n][kd]];
                s[n] = __builtin_amdgcn_mfma_f32_16x16x32_bf16(kf, qf[kd], s[n], 0, 0, 0);
            }
        }

        unsigned int pk[4][2];
        #pragma unroll
        for (int n = 0; n < 4; n++) {
            float p0 = exp2f(s[n][0]), p1 = exp2f(s[n][1]);
            float p2 = exp2f(s[n][2]), p3 = exp2f(s[n][3]);
            lsum += (p0 + p1) + (p2 + p3);
            pk[n][0] = cvtpk(p0, p1);
            pk[n][1] = cvtpk(p2, p3);
        }

        #pragma unroll
        for (int kk = 0; kk < 2; kk++) {
            bfr pa;
            pa.u[0] = pk[kk * 2][0];
            pa.u[1] = pk[kk * 2][1];
            pa.u[2] = __shfl_xor(pk[kk * 2 + 1][0], 32);
            pa.u[3] = __shfl_xor(pk[kk * 2 + 1][1], 32);
            #pragma unroll
            for (int n6 = 0; n6 < 6; n6++) {
                bf16x8 vf = *(const bf16x8*)&Vs[cur][vrd[n6][kk]];
                o[n6] = __builtin_amdgcn_mfma_f32_16x16x32_bf16(pa.v, vf, o[n6], 0, 0, 0);
            }
        }

        if (t < 15) {
            #pragma unroll
            for (int it = 0; it < 3; it++) {
                *(u16x8*)&Ks[cur ^ 1][kwr[it]] = kreg[it];
                *(u16x8*)&Vs[cur ^ 1][vwr[it]] = vreg[it];
            }
        }
        cur ^= 1;
    }

    lsum += __shfl_xor(lsum, 16);
    lsum += __shfl_xor(lsum, 32);
    float linv = 1.0f / lsum;

    const int b = bh >> 3, h = bh & 7;
    #pragma unroll
    for (int r = 0; r < 4; r++) {
        float lr = __shfl(linv, g * 4 + r);
        int row = qt * 64 + wid * 16 + g * 4 + r;
        long base = ((long)(b * 1024 + row)) * 768 + h * 96;
        #pragma unroll
        for (int n6 = 0; n6 < 6; n6++)
            Ob[base + n6 * 16 + i15] = f2bf(o[n6][r] * lr);
    }
}

// ---------------------------------------------------------------- out projection (BK=64) + residual + attn_map
__global__ __launch_bounds__(256) void out_k(
    const u16* __restrict__ Ob, const u16* __restrict__ WpT,
    const float* __restrict__ bp, const float* __restrict__ resid,
    float* __restrict__ out, float* __restrict__ amap)
{
    const int id = blockIdx.x;
    if (id >= 384) {
        amap[(id - 384) * 256 + threadIdx.x] = 1.0f;
        return;
    }
    __shared__ u16 As[128 * 64];
    __shared__ u16 Bs[128 * 64];
    const int swz = (id & 7) * 48 + (id >> 3);
    const int rt = swz / 6, ct = swz % 6;
    const int row0 = rt * 128, col0 = ct * 128;
    const int tid = threadIdx.x, lane = tid & 63, wid = tid >> 6;
    const int wr = wid >> 1, wc = wid & 1;
    const int g = lane >> 4, i15 = lane & 15;

    const u16* srcA[4]; const u16* srcB[4]; int dstOff[4];
    #pragma unroll
    for (int c = 0; c < 4; c++) {
        int d = tid + c * 256;
        int r = d >> 3, sl = d & 7;
        int colx = ((sl ^ (r & 7)) << 3);
        srcA[c] = Ob  + (long)(row0 + r) * 768 + colx;
        srcB[c] = WpT + (long)(col0 + r) * 768 + colx;
        dstOff[c] = (wid * 64 + c * 256) * 8;
    }

    int aoff[4][2], boff[4][2];
    #pragma unroll
    for (int m = 0; m < 4; m++) {
        int R = wr * 64 + m * 16 + i15;
        #pragma unroll
        for (int ks = 0; ks < 2; ks++)
            aoff[m][ks] = R * 64 + (((ks * 4 + g) ^ (R & 7)) << 3);
    }
    #pragma unroll
    for (int n = 0; n < 4; n++) {
        int R = wc * 64 + n * 16 + i15;
        #pragma unroll
        for (int ks = 0; ks < 2; ks++)
            boff[n][ks] = R * 64 + (((ks * 4 + g) ^ (R & 7)) << 3);
    }

    f32x4 acc[4][4] = {};
    for (int t = 0; t < 12; t++) {
        __syncthreads();
        #pragma unroll
        for (int c = 0; c < 4; c++) {
            gload16(srcA[c] + t * 64, &As[dstOff[c]]);
            gload16(srcB[c] + t * 64, &Bs[dstOff[c]]);
        }
        __syncthreads();
        #pragma unroll
        for (int ks = 0; ks < 2; ks++) {
            bf16x8 av[4], bv[4];
            #pragma unroll
            for (int m = 0; m < 4; m++) av[m] = *(const bf16x8*)&As[aoff[m][ks]];
            #pragma unroll
            for (int n = 0; n < 4; n++) bv[n] = *(const bf16x8*)&Bs[boff[n][ks]];
            #pragma unroll
            for (int m = 0; m < 4; m++)
                #pragma unroll
                for (int n = 0; n < 4; n++)
                    acc[m][n] = __builtin_amdgcn_mfma_f32_16x16x32_bf16(av[m], bv[n], acc[m][n], 0, 0, 0);
        }
    }

    float bv4[4];
    #pragma unroll
    for (int n = 0; n < 4; n++) bv4[n] = bp[col0 + wc * 64 + n * 16 + i15];

    #pragma unroll
    for (int m = 0; m < 4; m++) {
        #pragma unroll
        for (int n = 0; n < 4; n++) {
            const int col = col0 + wc * 64 + n * 16 + i15;
            #pragma unroll
            for (int r = 0; r < 4; r++) {
                const int row = row0 + wr * 64 + m * 16 + g * 4 + r;
                long idx = (long)row * 768 + col;
                out[idx] = acc[m][n][r] + bv4[n] + resid[idx];
            }
        }
    }
}

extern "C" void kernel_launch(void* const* d_in, const int* in_sizes, int n_in,
                              void* d_out, int out_size, void* d_ws, size_t ws_size,
                              hipStream_t stream)
{
    const float* x   = (const float*)d_in[0];
    const float* ctx = (const float*)d_in[1];
    const float* Wq  = (const float*)d_in[2];
    const float* bq  = (const float*)d_in[3];
    const float* Wkv = (const float*)d_in[4];
    const float* bkv = (const float*)d_in[5];
    const float* Wp  = (const float*)d_in[6];
    const float* bp  = (const float*)d_in[7];
    const float* g1  = (const float*)d_in[8];
    const float* b1  = (const float*)d_in[9];
    const float* g2  = (const float*)d_in[10];
    const float* b2  = (const float*)d_in[11];
    float* out = (float*)d_out;

    char* w = (char*)d_ws;
    const long SZ_ROWS = 8192L * 768 * 2;   // 12,582,912 B
    long off = 0;
    u16* xn   = (u16*)(w + off); off += SZ_ROWS;
    u16* cn   = (u16*)(w + off); off += SZ_ROWS;
    u16* WqT  = (u16*)(w + off); off += 768L * 768 * 2;
    u16* WkvT = (u16*)(w + off); off += 1536L * 768 * 2;
    u16* WpT  = (u16*)(w + off); off += 768L * 768 * 2;
    u16* Qb   = (u16*)(w + off); off += SZ_ROWS;
    u16* Kb   = (u16*)(w + off); off += SZ_ROWS;
    u16* Vt   = (u16*)(w + off); off += SZ_ROWS;
    u16* Ob   = (u16*)(w + off); off += SZ_ROWS;

    prep_ln_k<<<16960, 256, 0, stream>>>(x, ctx, g1, b1, g2, b2, Wq, Wkv, Wp,
                                         xn, cn, WqT, WkvT, WpT);
    qkv_k<<<1152, 256, 0, stream>>>(xn, cn, WqT, WkvT, bq, bkv, Qb, Kb, Vt);
    flash_k<<<1024, 256, 0, stream>>>(Qb, Kb, Vt, Ob);
    out_k<<<416, 256, 0, stream>>>(Ob, WpT, bp, x, out, out + 6291456L);
}

// Round 15
// 154.693 us; speedup vs baseline: 1.6363x; 1.0545x over previous
//
#include <hip/hip_runtime.h>

typedef unsigned short u16;
typedef short bf16x8 __attribute__((ext_vector_type(8)));
typedef float f32x4 __attribute__((ext_vector_type(4)));
typedef unsigned short u16x8 __attribute__((ext_vector_type(8)));
typedef unsigned short u16x4 __attribute__((ext_vector_type(4)));

union bfr { unsigned int u[4]; bf16x8 v; };

__device__ __forceinline__ u16 f2bf(float f) {
    unsigned int u = __builtin_bit_cast(unsigned int, f);
    u = (u + 0x7fffu + ((u >> 16) & 1u)) >> 16;
    return (u16)u;
}

// v_cvt_pk_bf16_f32: dst = [bf16(hi) : bf16(lo)] (RNE)
__device__ __forceinline__ unsigned int cvtpk(float lo, float hi) {
    unsigned int r;
    asm("v_cvt_pk_bf16_f32 %0, %1, %2" : "=v"(r) : "v"(lo), "v"(hi));
    return r;
}

// async 16B global -> LDS (dest = wave-uniform base + lane*16)
__device__ __forceinline__ void gload16(const u16* src, u16* lds_dst) {
    __builtin_amdgcn_global_load_lds(
        (const __attribute__((address_space(1))) unsigned int*)src,
        (__attribute__((address_space(3))) unsigned int*)lds_dst, 16, 0, 0);
}

// ---------------------------------------------------------------- prep: per-wave LN + tiled transpose
// id < 4096: 4 LN rows/block, one wave per row (no barriers, f32x4 loads).
// id >= 4096: 64x64 weight-transpose tiles (576 blocks), as before.
__global__ __launch_bounds__(256) void prep_ln_k(
    const float* __restrict__ x, const float* __restrict__ ctx,
    const float* __restrict__ g1, const float* __restrict__ b1,
    const float* __restrict__ g2, const float* __restrict__ b2,
    const float* __restrict__ Wq, const float* __restrict__ Wkv,
    const float* __restrict__ Wp,
    u16* __restrict__ xn, u16* __restrict__ cn,
    u16* __restrict__ WqT, u16* __restrict__ WkvT, u16* __restrict__ WpT)
{
    const int id = blockIdx.x;
    const int t = threadIdx.x;
    if (id >= 4096) {
        __shared__ float T[64][65];
        int t2 = id - 4096;
        const float* src; u16* dst; int lds, k0, n0;
        if (t2 < 288) { src = Wkv; dst = WkvT; lds = 1536; k0 = (t2 / 24) * 64; n0 = (t2 % 24) * 64; }
        else if (t2 < 432) { int u = t2 - 288; src = Wq; dst = WqT; lds = 768; k0 = (u / 12) * 64; n0 = (u % 12) * 64; }
        else { int u = t2 - 432; src = Wp; dst = WpT; lds = 768; k0 = (u / 12) * 64; n0 = (u % 12) * 64; }
        const int rr = t >> 4, c4 = (t & 15) * 4;
        #pragma unroll
        for (int it = 0; it < 4; it++) {
            int r = rr + it * 16;
            f32x4 v = *(const f32x4*)&src[(long)(k0 + r) * lds + n0 + c4];
            #pragma unroll
            for (int j = 0; j < 4; j++) T[c4 + j][r] = v[j];
        }
        __syncthreads();
        #pragma unroll
        for (int it = 0; it < 4; it++) {
            int r = rr + it * 16;
            u16x4 w;
            #pragma unroll
            for (int j = 0; j < 4; j++) w[j] = f2bf(T[r][c4 + j]);
            *(u16x4*)&dst[(long)(n0 + r) * 768 + k0 + c4] = w;
        }
        return;
    }
    // LN: wave w of this block handles row id*4 + w; lane owns 12 elems (3x f32x4)
    const int lane = t & 63, w = t >> 6;
    const int row = id * 4 + w;
    const float* src; const float* g; const float* b; u16* dst;
    if (row < 8192) { src = x + (long)row * 768; g = g1; b = b1; dst = xn + (long)row * 768; }
    else { int r = row - 8192; src = ctx + (long)r * 768; g = g2; b = b2; dst = cn + (long)r * 768; }

    const int c0 = lane * 4;
    f32x4 v0 = *(const f32x4*)&src[c0];
    f32x4 v1 = *(const f32x4*)&src[c0 + 256];
    f32x4 v2 = *(const f32x4*)&src[c0 + 512];
    float s = (v0[0] + v0[1] + v0[2] + v0[3]) + (v1[0] + v1[1] + v1[2] + v1[3])
            + (v2[0] + v2[1] + v2[2] + v2[3]);
    #pragma unroll
    for (int o = 32; o; o >>= 1) s += __shfl_xor(s, o);
    const float mu = s * (1.0f / 768.0f);
    float q = 0.f;
    #pragma unroll
    for (int j = 0; j < 4; j++) { float d = v0[j] - mu; q += d * d; }
    #pragma unroll
    for (int j = 0; j < 4; j++) { float d = v1[j] - mu; q += d * d; }
    #pragma unroll
    for (int j = 0; j < 4; j++) { float d = v2[j] - mu; q += d * d; }
    #pragma unroll
    for (int o = 32; o; o >>= 1) q += __shfl_xor(q, o);
    const float rs = rsqrtf(q * (1.0f / 768.0f) + 1e-5f);

    f32x4 ga0 = *(const f32x4*)&g[c0],       ba0 = *(const f32x4*)&b[c0];
    f32x4 ga1 = *(const f32x4*)&g[c0 + 256], ba1 = *(const f32x4*)&b[c0 + 256];
    f32x4 ga2 = *(const f32x4*)&g[c0 + 512], ba2 = *(const f32x4*)&b[c0 + 512];
    u16x4 w0, w1, w2;
    #pragma unroll
    for (int j = 0; j < 4; j++) {
        w0[j] = f2bf((v0[j] - mu) * rs * ga0[j] + ba0[j]);
        w1[j] = f2bf((v1[j] - mu) * rs * ga1[j] + ba1[j]);
        w2[j] = f2bf((v2[j] - mu) * rs * ga2[j] + ba2[j]);
    }
    *(u16x4*)&dst[c0]       = w0;
    *(u16x4*)&dst[c0 + 256] = w1;
    *(u16x4*)&dst[c0 + 512] = w2;
}

// ---------------------------------------------------------------- fused Q + KV projection
// r12 structure (2-sync 128x128 BK=32, conflict-free (r>>1)&3 twist) + NEW:
// per-block K-loop start stagger (accumulation is order-invariant) to dephase
// co-resident blocks' staging bursts (anti-convoy).
__global__ __launch_bounds__(256) void qkv_k(
    const u16* __restrict__ xn, const u16* __restrict__ cn,
    const u16* __restrict__ WqT, const u16* __restrict__ WkvT,
    const float* __restrict__ bq, const float* __restrict__ bkv,
    u16* __restrict__ Qb, u16* __restrict__ Kb, u16* __restrict__ Vt)
{
    __shared__ u16 As[128 * 32];
    __shared__ u16 Bs[128 * 32];
    const int id = blockIdx.x;
    const int swz = (id & 7) * 144 + (id >> 3);   // XCD-chunked over 1152
    const int tid = threadIdx.x, lane = tid & 63, wid = tid >> 6;
    const int wr = wid >> 1, wc = wid & 1;
    const int g = lane >> 4, i15 = lane & 15;

    const bool isQ = swz < 384;
    int rt, ct;
    const u16* A; const u16* Bt; const float* bias;
    if (isQ) { rt = swz / 6;  ct = swz % 6;  A = xn; Bt = WqT;  bias = bq; }
    else { int s2 = swz - 384; rt = s2 / 12; ct = s2 % 12; A = cn; Bt = WkvT; bias = bkv; }
    const int row0 = rt * 128, col0 = ct * 128;

    const u16* srcA[2]; const u16* srcB[2]; int ldsOff[2];
    #pragma unroll
    for (int c = 0; c < 2; c++) {
        int P0 = (wid * 2 + c) * 1024;
        int P = P0 + lane * 16;
        int r = P >> 6;
        int slot = (P >> 4) & 3;
        int colx = ((slot ^ ((r >> 1) & 3)) << 3);   // pre-swizzled source col
        srcA[c] = A  + (long)(row0 + r) * 768 + colx;
        srcB[c] = Bt + (long)(col0 + r) * 768 + colx;
        ldsOff[c] = P0 >> 1;
    }

    int aoff[4], boff[4];
    #pragma unroll
    for (int m = 0; m < 4; m++) {
        int R = wr * 64 + m * 16 + i15;
        aoff[m] = R * 32 + ((g ^ ((R >> 1) & 3)) << 3);
    }
    #pragma unroll
    for (int n = 0; n < 4; n++) {
        int R = wc * 64 + n * 16 + i15;
        boff[n] = R * 32 + ((g ^ ((R >> 1) & 3)) << 3);
    }

    f32x4 acc[4][4] = {};
    int kc = ((id >> 3) % 24) * 32;               // staggered K start (elems)
    for (int t = 0; t < 24; t++) {
        __syncthreads();
        #pragma unroll
        for (int c = 0; c < 2; c++) {
            gload16(srcA[c] + kc, &As[ldsOff[c]]);
            gload16(srcB[c] + kc, &Bs[ldsOff[c]]);
        }
        __syncthreads();
        bf16x8 av[4], bv[4];
        #pragma unroll
        for (int m = 0; m < 4; m++) av[m] = *(const bf16x8*)&As[aoff[m]];
        #pragma unroll
        for (int n = 0; n < 4; n++) bv[n] = *(const bf16x8*)&Bs[boff[n]];
        #pragma unroll
        for (int m = 0; m < 4; m++)
            #pragma unroll
            for (int n = 0; n < 4; n++)
                acc[m][n] = __builtin_amdgcn_mfma_f32_16x16x32_bf16(av[m], bv[n], acc[m][n], 0, 0, 0);
        kc += 32;
        if (kc == 768) kc = 0;
    }

    float bv4[4];
    #pragma unroll
    for (int n = 0; n < 4; n++) bv4[n] = bias[col0 + wc * 64 + n * 16 + i15];

    #pragma unroll
    for (int m = 0; m < 4; m++) {
        #pragma unroll
        for (int n = 0; n < 4; n++) {
            const int col = col0 + wc * 64 + n * 16 + i15;
            #pragma unroll
            for (int r = 0; r < 4; r++) {
                const int row = row0 + wr * 64 + m * 16 + g * 4 + r;
                float v = acc[m][n][r];
                if (isQ) {
                    v = (v + bv4[n]) * 0.14724444706f;   // 96^-0.5 * log2(e)
                    int b = row >> 10, l = row & 1023;
                    int h = col / 96, d = col % 96;
                    Qb[((long)(b * 8 + h) * 1024 + l) * 96 + d] = f2bf(v);
                } else {
                    v += bv4[n];
                    int b = row >> 10, mt = row & 1023;
                    if (col < 768) {
                        int h = col / 96, d = col % 96;
                        Kb[((long)(b * 8 + h) * 1024 + mt) * 96 + d] = f2bf(v);
                    } else {
                        int cc = col - 768;
                        int h = cc / 96, d = cc % 96;
                        Vt[((long)(b * 8 + h) * 96 + d) * 1024 + mt] = f2bf(v);
                    }
                }
            }
        }
    }
}

// ---------------------------------------------------------------- fused flash attention
// r12 internals + NEW: single-buffered K (post-QK barrier legalizes overwrite)
// -> LDS 48->36 KB -> 4 blocks/CU resident (grid needs exactly 4; was capped
// at 3 with one slot vacant). V stays double-buffered.
__global__ __launch_bounds__(256) void flash_k(
    const u16* __restrict__ Qb, const u16* __restrict__ Kb,
    const u16* __restrict__ Vt, u16* __restrict__ Ob)
{
    const int i = blockIdx.x;
    const int s8 = i >> 3;
    const int bh = (i & 7) * 8 + (s8 >> 4);   // XCD-grouped: 8 bh per XCD
    const int qt = s8 & 15;
    const int tid = threadIdx.x, lane = tid & 63, wid = tid >> 6;
    const int g = lane >> 4, i15 = lane & 15;

    __shared__ u16 Ks[6144];      // single buffer, 12 KB, twisted slots
    __shared__ u16 Vs[2][6144];   // [96][64] swizzled, 2 x 12 KB

    const long baseQK = (long)bh * 98304;
    const u16* Kt  = Kb + baseQK;
    const u16* Vtp = Vt + baseQK;

    bf16x8 qf[3];
    {
        const u16* qrow = Qb + baseQK + (long)(qt * 64 + wid * 16 + i15) * 96 + g * 8;
        qf[0] = *(const bf16x8*)(qrow);
        qf[1] = *(const bf16x8*)(qrow + 32);
        qf[2] = *(const bf16x8*)(qrow + 64);
    }

    int krd[4][3];
    #pragma unroll
    for (int n = 0; n < 4; n++) {
        int q4 = i15 >> 2, rr = i15 & 3, m = n >> 1;
        int R = (n & 1) ? (m * 32 + ((q4 ^ 2) << 3) + 4 + rr)
                        : (m * 32 + (q4 << 3) + rr);
        #pragma unroll
        for (int kd = 0; kd < 3; kd++)
            krd[n][kd] = kd * 2048 + R * 32 + ((g ^ ((R >> 3) & 3) ^ kd) << 3);
    }
    int vrd[6][2];
    #pragma unroll
    for (int n6 = 0; n6 < 6; n6++) {
        int row = n6 * 16 + i15;
        #pragma unroll
        for (int kk = 0; kk < 2; kk++)
            vrd[n6][kk] = row * 64 + ((kk * 32 + g * 8) ^ ((row & 7) << 3));
    }

    int kgo[3], kwr[3], vgo[3], vwr[3];
    #pragma unroll
    for (int it = 0; it < 3; it++) {
        int e = tid + it * 256;
        int r = e / 12, cEl = (e % 12) * 8;
        int kd = cEl >> 5, slot = (cEl >> 3) & 3;
        kgo[it] = r * 96 + cEl;
        kwr[it] = kd * 2048 + r * 32 + ((slot ^ ((r >> 3) & 3) ^ kd) << 3);
        int d = e >> 3, m8 = (e & 7) * 8;
        vgo[it] = d * 1024 + m8;
        vwr[it] = d * 64 + (m8 ^ ((d & 7) << 3));
    }

    u16x8 kreg[3], vreg[3];
    #pragma unroll
    for (int it = 0; it < 3; it++) {
        kreg[it] = *(const u16x8*)&Kt[kgo[it]];
        vreg[it] = *(const u16x8*)&Vtp[vgo[it]];
    }
    #pragma unroll
    for (int it = 0; it < 3; it++) {
        *(u16x8*)&Ks[kwr[it]] = kreg[it];
        *(u16x8*)&Vs[0][vwr[it]] = vreg[it];
    }

    f32x4 o[6] = {};
    float lsum = 0.f;
    int cur = 0;

    for (int t = 0; t < 16; t++) {
        __syncthreads();                      // K/V(t) visible; prev writes done
        if (t < 15) {
            #pragma unroll
            for (int it = 0; it < 3; it++) {
                kreg[it] = *(const u16x8*)&Kt[(t + 1) * 6144 + kgo[it]];
                vreg[it] = *(const u16x8*)&Vtp[(t + 1) * 64 + vgo[it]];
            }
        }

        // QK^T from single-buffer Ks
        f32x4 s[4] = {};
        #pragma unroll
        for (int kd = 0; kd < 3; kd++) {
            #pragma unroll
            for (int n = 0; n < 4; n++) {
                bf16x8 kf = *(const bf16x8*)&Ks[krd[n][kd]];
                s[n] = __builtin_amdgcn_mfma_f32_16x16x32_bf16(kf, qf[kd], s[n], 0, 0, 0);
            }
        }
        __syncthreads();                      // all waves done reading Ks
        if (t < 15) {
            #pragma unroll
            for (int it = 0; it < 3; it++)
                *(u16x8*)&Ks[kwr[it]] = kreg[it];   // overwrite legal now
        }

        unsigned int pk[4][2];
        #pragma unroll
        for (int n = 0; n < 4; n++) {
            float p0 = exp2f(s[n][0]), p1 = exp2f(s[n][1]);
            float p2 = exp2f(s[n][2]), p3 = exp2f(s[n][3]);
            lsum += (p0 + p1) + (p2 + p3);
            pk[n][0] = cvtpk(p0, p1);
            pk[n][1] = cvtpk(p2, p3);
        }

        #pragma unroll
        for (int kk = 0; kk < 2; kk++) {
            bfr pa;
            pa.u[0] = pk[kk * 2][0];
            pa.u[1] = pk[kk * 2][1];
            pa.u[2] = __shfl_xor(pk[kk * 2 + 1][0], 32);
            pa.u[3] = __shfl_xor(pk[kk * 2 + 1][1], 32);
            #pragma unroll
            for (int n6 = 0; n6 < 6; n6++) {
                bf16x8 vf = *(const bf16x8*)&Vs[cur][vrd[n6][kk]];
                o[n6] = __builtin_amdgcn_mfma_f32_16x16x32_bf16(pa.v, vf, o[n6], 0, 0, 0);
            }
        }

        if (t < 15) {
            #pragma unroll
            for (int it = 0; it < 3; it++)
                *(u16x8*)&Vs[cur ^ 1][vwr[it]] = vreg[it];
        }
        cur ^= 1;
    }

    lsum += __shfl_xor(lsum, 16);
    lsum += __shfl_xor(lsum, 32);
    float linv = 1.0f / lsum;

    const int b = bh >> 3, h = bh & 7;
    #pragma unroll
    for (int r = 0; r < 4; r++) {
        float lr = __shfl(linv, g * 4 + r);
        int row = qt * 64 + wid * 16 + g * 4 + r;
        long base = ((long)(b * 1024 + row)) * 768 + h * 96;
        #pragma unroll
        for (int n6 = 0; n6 < 6; n6++)
            Ob[base + n6 * 16 + i15] = f2bf(o[n6][r] * lr);
    }
}

// ---------------------------------------------------------------- out projection + residual + attn_map (r12)
__global__ __launch_bounds__(256) void out_k(
    const u16* __restrict__ Ob, const u16* __restrict__ WpT,
    const float* __restrict__ bp, const float* __restrict__ resid,
    float* __restrict__ out, float* __restrict__ amap)
{
    const int id = blockIdx.x;
    if (id >= 384) {
        amap[(id - 384) * 256 + threadIdx.x] = 1.0f;
        return;
    }
    __shared__ u16 As[128 * 32];
    __shared__ u16 Bs[128 * 32];
    const int swz = (id & 7) * 48 + (id >> 3);
    const int rt = swz / 6, ct = swz % 6;
    const int row0 = rt * 128, col0 = ct * 128;
    const int tid = threadIdx.x, lane = tid & 63, wid = tid >> 6;
    const int wr = wid >> 1, wc = wid & 1;
    const int g = lane >> 4, i15 = lane & 15;

    const u16* srcA[2]; const u16* srcB[2]; int ldsOff[2];
    #pragma unroll
    for (int c = 0; c < 2; c++) {
        int P0 = (wid * 2 + c) * 1024;
        int P = P0 + lane * 16;
        int r = P >> 6;
        int slot = (P >> 4) & 3;
        int colx = ((slot ^ ((r >> 1) & 3)) << 3);
        srcA[c] = Ob  + (long)(row0 + r) * 768 + colx;
        srcB[c] = WpT + (long)(col0 + r) * 768 + colx;
        ldsOff[c] = P0 >> 1;
    }

    int aoff[4], boff[4];
    #pragma unroll
    for (int m = 0; m < 4; m++) {
        int R = wr * 64 + m * 16 + i15;
        aoff[m] = R * 32 + ((g ^ ((R >> 1) & 3)) << 3);
    }
    #pragma unroll
    for (int n = 0; n < 4; n++) {
        int R = wc * 64 + n * 16 + i15;
        boff[n] = R * 32 + ((g ^ ((R >> 1) & 3)) << 3);
    }

    f32x4 acc[4][4] = {};
    for (int k0 = 0; k0 < 768; k0 += 32) {
        __syncthreads();
        #pragma unroll
        for (int c = 0; c < 2; c++) {
            gload16(srcA[c] + k0, &As[ldsOff[c]]);
            gload16(srcB[c] + k0, &Bs[ldsOff[c]]);
        }
        __syncthreads();
        bf16x8 av[4], bv[4];
        #pragma unroll
        for (int m = 0; m < 4; m++) av[m] = *(const bf16x8*)&As[aoff[m]];
        #pragma unroll
        for (int n = 0; n < 4; n++) bv[n] = *(const bf16x8*)&Bs[boff[n]];
        #pragma unroll
        for (int m = 0; m < 4; m++)
            #pragma unroll
            for (int n = 0; n < 4; n++)
                acc[m][n] = __builtin_amdgcn_mfma_f32_16x16x32_bf16(av[m], bv[n], acc[m][n], 0, 0, 0);
    }

    float bv4[4];
    #pragma unroll
    for (int n = 0; n < 4; n++) bv4[n] = bp[col0 + wc * 64 + n * 16 + i15];

    #pragma unroll
    for (int m = 0; m < 4; m++) {
        #pragma unroll
        for (int n = 0; n < 4; n++) {
            const int col = col0 + wc * 64 + n * 16 + i15;
            #pragma unroll
            for (int r = 0; r < 4; r++) {
                const int row = row0 + wr * 64 + m * 16 + g * 4 + r;
                long idx = (long)row * 768 + col;
                out[idx] = acc[m][n][r] + bv4[n] + resid[idx];
            }
        }
    }
}

extern "C" void kernel_launch(void* const* d_in, const int* in_sizes, int n_in,
                              void* d_out, int out_size, void* d_ws, size_t ws_size,
                              hipStream_t stream)
{
    const float* x   = (const float*)d_in[0];
    const float* ctx = (const float*)d_in[1];
    const float* Wq  = (const float*)d_in[2];
    const float* bq  = (const float*)d_in[3];
    const float* Wkv = (const float*)d_in[4];
    const float* bkv = (const float*)d_in[5];
    const float* Wp  = (const float*)d_in[6];
    const float* bp  = (const float*)d_in[7];
    const float* g1  = (const float*)d_in[8];
    const float* b1  = (const float*)d_in[9];
    const float* g2  = (const float*)d_in[10];
    const float* b2  = (const float*)d_in[11];
    float* out = (float*)d_out;

    char* w = (char*)d_ws;
    const long SZ_ROWS = 8192L * 768 * 2;   // 12,582,912 B
    long off = 0;
    u16* xn   = (u16*)(w + off); off += SZ_ROWS;
    u16* cn   = (u16*)(w + off); off += SZ_ROWS;
    u16* WqT  = (u16*)(w + off); off += 768L * 768 * 2;
    u16* WkvT = (u16*)(w + off); off += 1536L * 768 * 2;
    u16* WpT  = (u16*)(w + off); off += 768L * 768 * 2;
    u16* Qb   = (u16*)(w + off); off += SZ_ROWS;
    u16* Kb   = (u16*)(w + off); off += SZ_ROWS;
    u16* Vt   = (u16*)(w + off); off += SZ_ROWS;
    u16* Ob   = (u16*)(w + off); off += SZ_ROWS;

    prep_ln_k<<<4672, 256, 0, stream>>>(x, ctx, g1, b1, g2, b2, Wq, Wkv, Wp,
                                        xn, cn, WqT, WkvT, WpT);
    qkv_k<<<1152, 256, 0, stream>>>(xn, cn, WqT, WkvT, bq, bkv, Qb, Kb, Vt);
    flash_k<<<1024, 256, 0, stream>>>(Qb, Kb, Vt, Ob);
    out_k<<<416, 256, 0, stream>>>(Ob, WpT, bp, x, out, out + 6291456L);
}